// Round 1
// baseline (471.396 us; speedup 1.0000x reference)
//
#include <hip/hip_runtime.h>
#include <stdint.h>

typedef unsigned short u16;
typedef unsigned int   u32;
typedef __bf16 bf16x8 __attribute__((ext_vector_type(8)));
typedef float  f32x4  __attribute__((ext_vector_type(4)));
typedef u32    u32x4  __attribute__((ext_vector_type(4)));

#define L_IN 784
#define KPAD 832
#define KT_N 13

__device__ __forceinline__ u32 f2bf(float f){
    u32 u = __float_as_uint(f);
    return (u + 0x7fffu + ((u >> 16) & 1u)) >> 16;   // RNE truncate to bf16
}
__device__ __forceinline__ float bf2f(u32 s){ return __uint_as_float(s << 16); }

// ---------------------------------------------------------------------------
// K0: convert W0 [784][128] f32 -> bf16, K-tiled (13 tiles of 64, zero-padded)
// and pre-swizzled into the LDS image layout: per tile, [col][k] with the
// 16B-slot XOR swizzle baked in so GEMM can copy it linearly.
// ---------------------------------------------------------------------------
__global__ void prep_w0(const float* __restrict__ W0, u16* __restrict__ W0sw){
    int idx = blockIdx.x * 256 + threadIdx.x;        // 832*128 = 106496 total
    if (idx >= KPAD * 128) return;
    int kpad = idx >> 7, col = idx & 127;
    int kt = kpad >> 6, kin = kpad & 63;
    float v = (kpad < L_IN) ? W0[kpad * 128 + col] : 0.f;
    int swz_half = ((kin * 2) ^ ((col & 7) << 4)) >> 1;  // swizzled ushort slot
    W0sw[kt * 8192 + col * 64 + swz_half] = (u16)f2bf(v);
}

// ---------------------------------------------------------------------------
// K1: x = relu(h @ W0 + b0), bf16 MFMA GEMM, 128x128 tile, BK=64, 13 K-steps.
// MFMA K-permutation invariance: A and B use the same assumed k-slot mapping,
// so the accumulated dot product is exact regardless of the true HW K layout.
// ---------------------------------------------------------------------------
__global__ __launch_bounds__(256, 2)
void fc_gemm(const float* __restrict__ hG, const u16* __restrict__ W0sw,
             const float* __restrict__ b0, u16* __restrict__ xbf, int N){
    __shared__ __align__(16) u16 As[128 * 72];   // padded row stride 72 bf16 = 144B
    __shared__ __align__(16) u16 Bs[8192];       // [col][k] swizzled image, 16KB

    const int t    = threadIdx.x;
    const int lane = t & 63;
    const int w    = t >> 6;
    const int gb   = blockIdx.x;

    const int  rowA = t >> 1;            // 0..127
    const int  kseg = t & 1;             // 32-k half
    const long grow = (long)gb * 128 + rowA;

    f32x4 acc[2][8];
    #pragma unroll
    for (int i = 0; i < 2; ++i)
        #pragma unroll
        for (int j = 0; j < 8; ++j)
            acc[i][j] = (f32x4)0.f;

    for (int kt = 0; kt < KT_N; ++kt){
        // ---- stage A: global f32 -> bf16 -> LDS (padded stride) ----
        {
            u32 pk[16];
            #pragma unroll
            for (int c2 = 0; c2 < 8; ++c2){
                int k = kt * 64 + kseg * 32 + c2 * 4;
                float4 v = make_float4(0.f, 0.f, 0.f, 0.f);
                if (grow < (long)N && k < L_IN)
                    v = *(const float4*)(hG + grow * L_IN + k);
                pk[c2 * 2 + 0] = f2bf(v.x) | (f2bf(v.y) << 16);
                pk[c2 * 2 + 1] = f2bf(v.z) | (f2bf(v.w) << 16);
            }
            #pragma unroll
            for (int c4 = 0; c4 < 4; ++c4){
                u32x4 val;
                val[0] = pk[c4*4+0]; val[1] = pk[c4*4+1];
                val[2] = pk[c4*4+2]; val[3] = pk[c4*4+3];
                *(u32x4*)((char*)As + rowA * 144 + kseg * 64 + c4 * 16) = val;
            }
        }
        // ---- stage B: pre-swizzled bf16 image, linear copy ----
        #pragma unroll
        for (int p = 0; p < 4; ++p){
            u32x4 v = *(const u32x4*)(W0sw + kt * 8192 + p * 2048 + t * 8);
            *(u32x4*)(Bs + p * 2048 + t * 8) = v;
        }
        __syncthreads();

        // ---- compute: wave w owns rows [w*32, w*32+32), all 128 cols ----
        #pragma unroll
        for (int kk = 0; kk < 2; ++kk){
            bf16x8 a[2], b[8];
            #pragma unroll
            for (int mt = 0; mt < 2; ++mt){
                int row = w * 32 + mt * 16 + (lane & 15);
                a[mt] = *(const bf16x8*)((const char*)As + row * 144 + kk * 64 + ((lane >> 4) * 16));
            }
            #pragma unroll
            for (int nt = 0; nt < 8; ++nt){
                int col = nt * 16 + (lane & 15);
                int kb  = (kk * 64 + ((lane >> 4) * 16)) ^ ((col & 7) << 4);
                b[nt] = *(const bf16x8*)((const char*)Bs + col * 128 + kb);
            }
            #pragma unroll
            for (int mt = 0; mt < 2; ++mt)
                #pragma unroll
                for (int nt = 0; nt < 8; ++nt)
                    acc[mt][nt] = __builtin_amdgcn_mfma_f32_16x16x32_bf16(a[mt], b[nt], acc[mt][nt], 0, 0, 0);
        }
        __syncthreads();
    }

    // ---- epilogue: + bias, relu, store bf16 ----
    #pragma unroll
    for (int nt = 0; nt < 8; ++nt){
        int col = nt * 16 + (lane & 15);
        float bias = b0[col];
        #pragma unroll
        for (int mt = 0; mt < 2; ++mt){
            long row0 = (long)gb * 128 + w * 32 + mt * 16 + ((lane >> 4) * 4);
            #pragma unroll
            for (int r = 0; r < 4; ++r){
                long row = row0 + r;
                if (row < (long)N){
                    float v = acc[mt][nt][r] + bias;
                    v = v > 0.f ? v : 0.f;
                    xbf[(size_t)row * 128 + col] = (u16)f2bf(v);
                }
            }
        }
    }
}

// ---------------------------------------------------------------------------
// K2: gated attention logits + exp + block pooling partials.
// ---------------------------------------------------------------------------
__global__ __launch_bounds__(256, 2)
void attn_pool(const u16* __restrict__ xbf,
               const float* __restrict__ Wa, const float* __restrict__ ba,
               const float* __restrict__ Wb, const float* __restrict__ bb,
               const float* __restrict__ Wc, const float* __restrict__ bc,
               float* __restrict__ partials, float* __restrict__ psum, int N){
    __shared__ __align__(16) float Wa_s[4096], Wb_s[4096];
    __shared__ float ba_s[64], bb_s[64], Wc_s[64], bc_s[2];
    __shared__ float eA[128][2];

    const int t  = threadIdx.x;
    const int gb = blockIdx.x;

    for (int i = t; i < 4096; i += 256){ Wa_s[i] = Wa[i]; Wb_s[i] = Wb[i]; }
    if (t < 64){ ba_s[t] = ba[t]; bb_s[t] = bb[t]; Wc_s[t] = Wc[t]; }
    if (t < 2)  bc_s[t] = bc[t];
    __syncthreads();

    // ---- phase 1: attention logit per (instance, head) ----
    {
        const int inst = t & 127, hh = t >> 7;
        const long gi = (long)gb * 128 + inst;
        float aa[32], ag[32];
        #pragma unroll
        for (int d = 0; d < 32; ++d){ aa[d] = ba_s[hh*32+d]; ag[d] = bb_s[hh*32+d]; }
        const float* wa = &Wa_s[hh * 2048];
        const float* wb = &Wb_s[hh * 2048];
        const u16*   xp = xbf + gi * 128 + hh * 64;
        for (int c = 0; c < 8; ++c){
            u32x4 xc = *(const u32x4*)(xp + c * 8);
            #pragma unroll
            for (int s8 = 0; s8 < 8; ++s8){
                u32 uw = xc[s8 >> 1];
                float xv = bf2f((s8 & 1) ? (uw >> 16) : (uw & 0xffffu));
                const int s = c * 8 + s8;
                #pragma unroll
                for (int q = 0; q < 8; ++q){
                    f32x4 w4 = *(const f32x4*)(wa + s * 32 + q * 4);
                    f32x4 v4 = *(const f32x4*)(wb + s * 32 + q * 4);
                    aa[q*4+0] += xv * w4[0]; aa[q*4+1] += xv * w4[1];
                    aa[q*4+2] += xv * w4[2]; aa[q*4+3] += xv * w4[3];
                    ag[q*4+0] += xv * v4[0]; ag[q*4+1] += xv * v4[1];
                    ag[q*4+2] += xv * v4[2]; ag[q*4+3] += xv * v4[3];
                }
            }
        }
        float A = bc_s[hh];
        #pragma unroll
        for (int d = 0; d < 32; ++d){
            float av = tanhf(aa[d]);
            float gv = 1.f / (1.f + expf(-ag[d]));
            A += av * gv * Wc_s[hh*32+d];
        }
        // exp without max-subtraction: |A| <= sum|Wc|+|bc| (~7), safe in f32.
        eA[inst][hh] = (gi < (long)N) ? expf(A) : 0.f;
    }
    __syncthreads();

    if (t < 2){
        float s = 0.f;
        for (int i = 0; i < 128; ++i) s += eA[i][t];
        psum[gb * 2 + t] = s;
    }

    // ---- phase 2: pooling partials sum(e * x) over this block's instances ----
    {
        const int ui = t >> 2, q = t & 3;   // ui: uint channel 0..63, q: quarter
        const int hh = ui >> 5;
        float p0 = 0.f, p1 = 0.f;
        #pragma unroll 4
        for (int i = 0; i < 32; ++i){
            const int inst = q * 32 + i;
            u32 u = *(const u32*)(xbf + ((long)gb * 128 + inst) * 128 + ui * 2);
            float e = eA[inst][hh];
            p0 += e * bf2f(u & 0xffffu);
            p1 += e * bf2f(u >> 16);
        }
        partials[(size_t)gb * 512 + ui * 8 + 0 + q] = p0;
        partials[(size_t)gb * 512 + ui * 8 + 4 + q] = p1;
    }
}

// ---------------------------------------------------------------------------
// K3: combine partials (f64), M, logits, sigmoid, Y_hat. One block.
// ---------------------------------------------------------------------------
__global__ void finalize(const float* __restrict__ partials, const float* __restrict__ psum,
                         const float* __restrict__ Wcls, const float* __restrict__ bcls,
                         float* __restrict__ out, int nb){
    __shared__ double den[2];
    __shared__ float  M_s[128];
    const int t = threadIdx.x;
    if (t < 2){
        double s = 0.0;
        for (int b = 0; b < nb; ++b) s += (double)psum[b * 2 + t];
        den[t] = s;
    }
    __syncthreads();
    if (t < 128){
        const int u2 = t >> 1, c = t & 1;       // channel = u2*2 + c = t
        double s = 0.0;
        for (int b = 0; b < nb; ++b){
            const float* p = partials + (size_t)b * 512 + u2 * 8 + c * 4;
            s += (double)p[0] + (double)p[1] + (double)p[2] + (double)p[3];
        }
        M_s[t] = (float)(s / den[t >> 6]);
    }
    __syncthreads();
    if (t == 0){
        double lg = (double)bcls[0];
        for (int c2 = 0; c2 < 128; ++c2) lg += (double)M_s[c2] * (double)Wcls[c2];
        float p = (float)(1.0 / (1.0 + exp(-lg)));
        out[0] = p;
        out[1] = (lg >= 0.0) ? 1.f : 0.f;
    }
}

// ---------------------------------------------------------------------------
extern "C" void kernel_launch(void* const* d_in, const int* in_sizes, int n_in,
                              void* d_out, int out_size, void* d_ws, size_t ws_size,
                              hipStream_t stream){
    const float* hG   = (const float*)d_in[0];
    const float* W0   = (const float*)d_in[1];
    const float* b0   = (const float*)d_in[2];
    const float* Wa   = (const float*)d_in[3];
    const float* ba   = (const float*)d_in[4];
    const float* Wb   = (const float*)d_in[5];
    const float* bb   = (const float*)d_in[6];
    const float* Wc   = (const float*)d_in[7];
    const float* bc   = (const float*)d_in[8];
    const float* Wcls = (const float*)d_in[9];
    const float* bcls = (const float*)d_in[10];

    const int N  = in_sizes[0] / L_IN;
    const int nb = (N + 127) / 128;

    char* ws = (char*)d_ws;
    u16* W0sw = (u16*)ws;                                  // 13*8192*2 = 212992 B
    u16* xbf  = (u16*)(ws + 262144);                       // nb*128*128*2 B
    size_t xbytes = (size_t)nb * 128 * 128 * 2;
    size_t poff   = 262144 + ((xbytes + 4095) & ~(size_t)4095);
    float* partials = (float*)(ws + poff);                 // nb*512 f32
    float* psum     = partials + (size_t)nb * 512;         // nb*2 f32

    prep_w0 <<<(KPAD * 128) / 256, 256, 0, stream>>>(W0, W0sw);
    fc_gemm <<<nb, 256, 0, stream>>>(hG, W0sw, b0, xbf, N);
    attn_pool<<<nb, 256, 0, stream>>>(xbf, Wa, ba, Wb, bb, Wc, bc, partials, psum, N);
    finalize<<<1, 256, 0, stream>>>(partials, psum, Wcls, bcls, (float*)d_out, nb);
}

// Round 2
// 229.940 us; speedup vs baseline: 2.0501x; 2.0501x over previous
//
#include <hip/hip_runtime.h>
#include <stdint.h>

typedef unsigned short u16;
typedef unsigned int   u32;
typedef __bf16 bf16x8 __attribute__((ext_vector_type(8)));
typedef float  f32x4  __attribute__((ext_vector_type(4)));
typedef u32    u32x4  __attribute__((ext_vector_type(4)));

#define L_IN 784
#define KPAD 832
#define KT_N 13

__device__ __forceinline__ u32 f2bf(float f){
    u32 u = __float_as_uint(f);
    return (u + 0x7fffu + ((u >> 16) & 1u)) >> 16;   // RNE truncate to bf16
}
__device__ __forceinline__ float bf2f(u32 s){ return __uint_as_float(s << 16); }

// ---------------------------------------------------------------------------
// K0: convert W0 [784][128] f32 -> bf16, K-tiled (13 tiles of 64, zero-padded)
// and pre-swizzled into the LDS image layout.
// ---------------------------------------------------------------------------
__global__ void prep_w0(const float* __restrict__ W0, u16* __restrict__ W0sw){
    int idx = blockIdx.x * 256 + threadIdx.x;        // 832*128 = 106496 total
    if (idx >= KPAD * 128) return;
    int kpad = idx >> 7, col = idx & 127;
    int kt = kpad >> 6, kin = kpad & 63;
    float v = (kpad < L_IN) ? W0[kpad * 128 + col] : 0.f;
    int swz_half = ((kin * 2) ^ ((col & 7) << 4)) >> 1;  // swizzled ushort slot
    W0sw[kt * 8192 + col * 64 + swz_half] = (u16)f2bf(v);
}

// ---------------------------------------------------------------------------
// K1: x = relu(h @ W0 + b0), bf16 MFMA GEMM, 128x128 tile, BK=64, 13 K-steps.
// ---------------------------------------------------------------------------
__global__ __launch_bounds__(256, 2)
void fc_gemm(const float* __restrict__ hG, const u16* __restrict__ W0sw,
             const float* __restrict__ b0, u16* __restrict__ xbf, int N){
    __shared__ __align__(16) u16 As[128 * 72];   // padded row stride 72 bf16 = 144B
    __shared__ __align__(16) u16 Bs[8192];       // [col][k] swizzled image, 16KB

    const int t    = threadIdx.x;
    const int lane = t & 63;
    const int w    = t >> 6;
    const int gb   = blockIdx.x;

    const int  rowA = t >> 1;            // 0..127
    const int  kseg = t & 1;             // 32-k half
    const long grow = (long)gb * 128 + rowA;

    f32x4 acc[2][8];
    #pragma unroll
    for (int i = 0; i < 2; ++i)
        #pragma unroll
        for (int j = 0; j < 8; ++j)
            acc[i][j] = (f32x4)0.f;

    for (int kt = 0; kt < KT_N; ++kt){
        // ---- stage A: global f32 -> bf16 -> LDS (padded stride) ----
        {
            u32 pk[16];
            #pragma unroll
            for (int c2 = 0; c2 < 8; ++c2){
                int k = kt * 64 + kseg * 32 + c2 * 4;
                float4 v = make_float4(0.f, 0.f, 0.f, 0.f);
                if (grow < (long)N && k < L_IN)
                    v = *(const float4*)(hG + grow * L_IN + k);
                pk[c2 * 2 + 0] = f2bf(v.x) | (f2bf(v.y) << 16);
                pk[c2 * 2 + 1] = f2bf(v.z) | (f2bf(v.w) << 16);
            }
            #pragma unroll
            for (int c4 = 0; c4 < 4; ++c4){
                u32x4 val;
                val[0] = pk[c4*4+0]; val[1] = pk[c4*4+1];
                val[2] = pk[c4*4+2]; val[3] = pk[c4*4+3];
                *(u32x4*)((char*)As + rowA * 144 + kseg * 64 + c4 * 16) = val;
            }
        }
        // ---- stage B: pre-swizzled bf16 image, linear copy ----
        #pragma unroll
        for (int p = 0; p < 4; ++p){
            u32x4 v = *(const u32x4*)(W0sw + kt * 8192 + p * 2048 + t * 8);
            *(u32x4*)(Bs + p * 2048 + t * 8) = v;
        }
        __syncthreads();

        // ---- compute: wave w owns rows [w*32, w*32+32), all 128 cols ----
        #pragma unroll
        for (int kk = 0; kk < 2; ++kk){
            bf16x8 a[2], b[8];
            #pragma unroll
            for (int mt = 0; mt < 2; ++mt){
                int row = w * 32 + mt * 16 + (lane & 15);
                a[mt] = *(const bf16x8*)((const char*)As + row * 144 + kk * 64 + ((lane >> 4) * 16));
            }
            #pragma unroll
            for (int nt = 0; nt < 8; ++nt){
                int col = nt * 16 + (lane & 15);
                int kb  = (kk * 64 + ((lane >> 4) * 16)) ^ ((col & 7) << 4);
                b[nt] = *(const bf16x8*)((const char*)Bs + col * 128 + kb);
            }
            #pragma unroll
            for (int mt = 0; mt < 2; ++mt)
                #pragma unroll
                for (int nt = 0; nt < 8; ++nt)
                    acc[mt][nt] = __builtin_amdgcn_mfma_f32_16x16x32_bf16(a[mt], b[nt], acc[mt][nt], 0, 0, 0);
        }
        __syncthreads();
    }

    // ---- epilogue: + bias, relu, store bf16 ----
    #pragma unroll
    for (int nt = 0; nt < 8; ++nt){
        int col = nt * 16 + (lane & 15);
        float bias = b0[col];
        #pragma unroll
        for (int mt = 0; mt < 2; ++mt){
            long row0 = (long)gb * 128 + w * 32 + mt * 16 + ((lane >> 4) * 4);
            #pragma unroll
            for (int r = 0; r < 4; ++r){
                long row = row0 + r;
                if (row < (long)N){
                    float v = acc[mt][nt][r] + bias;
                    v = v > 0.f ? v : 0.f;
                    xbf[(size_t)row * 128 + col] = (u16)f2bf(v);
                }
            }
        }
    }
}

// ---------------------------------------------------------------------------
// K2: gated attention logits + exp + block pooling partials.
// ---------------------------------------------------------------------------
__global__ __launch_bounds__(256, 2)
void attn_pool(const u16* __restrict__ xbf,
               const float* __restrict__ Wa, const float* __restrict__ ba,
               const float* __restrict__ Wb, const float* __restrict__ bb,
               const float* __restrict__ Wc, const float* __restrict__ bc,
               float* __restrict__ partials, float* __restrict__ psum, int N){
    __shared__ __align__(16) float Wa_s[4096], Wb_s[4096];
    __shared__ float ba_s[64], bb_s[64], Wc_s[64], bc_s[2];
    __shared__ float eA[128][2];

    const int t  = threadIdx.x;
    const int gb = blockIdx.x;

    for (int i = t; i < 4096; i += 256){ Wa_s[i] = Wa[i]; Wb_s[i] = Wb[i]; }
    if (t < 64){ ba_s[t] = ba[t]; bb_s[t] = bb[t]; Wc_s[t] = Wc[t]; }
    if (t < 2)  bc_s[t] = bc[t];
    __syncthreads();

    // ---- phase 1: attention logit per (instance, head) ----
    {
        const int inst = t & 127, hh = t >> 7;
        const long gi = (long)gb * 128 + inst;
        float aa[32], ag[32];
        #pragma unroll
        for (int d = 0; d < 32; ++d){ aa[d] = ba_s[hh*32+d]; ag[d] = bb_s[hh*32+d]; }
        const float* wa = &Wa_s[hh * 2048];
        const float* wb = &Wb_s[hh * 2048];
        const u16*   xp = xbf + gi * 128 + hh * 64;
        for (int c = 0; c < 8; ++c){
            u32x4 xc = *(const u32x4*)(xp + c * 8);
            #pragma unroll
            for (int s8 = 0; s8 < 8; ++s8){
                u32 uw = xc[s8 >> 1];
                float xv = bf2f((s8 & 1) ? (uw >> 16) : (uw & 0xffffu));
                const int s = c * 8 + s8;
                #pragma unroll
                for (int q = 0; q < 8; ++q){
                    f32x4 w4 = *(const f32x4*)(wa + s * 32 + q * 4);
                    f32x4 v4 = *(const f32x4*)(wb + s * 32 + q * 4);
                    aa[q*4+0] += xv * w4[0]; aa[q*4+1] += xv * w4[1];
                    aa[q*4+2] += xv * w4[2]; aa[q*4+3] += xv * w4[3];
                    ag[q*4+0] += xv * v4[0]; ag[q*4+1] += xv * v4[1];
                    ag[q*4+2] += xv * v4[2]; ag[q*4+3] += xv * v4[3];
                }
            }
        }
        float A = bc_s[hh];
        #pragma unroll
        for (int d = 0; d < 32; ++d){
            float av = tanhf(aa[d]);
            float gv = 1.f / (1.f + expf(-ag[d]));
            A += av * gv * Wc_s[hh*32+d];
        }
        // exp without max-subtraction: |A| <= sum|Wc|+|bc| (~7), safe in f32.
        eA[inst][hh] = (gi < (long)N) ? expf(A) : 0.f;
    }
    __syncthreads();

    if (t < 2){
        float s = 0.f;
        for (int i = 0; i < 128; ++i) s += eA[i][t];
        psum[gb * 2 + t] = s;
    }

    // ---- phase 2: pooling partials sum(e * x) over this block's instances ----
    {
        const int ui = t >> 2, q = t & 3;   // ui: uint channel 0..63, q: quarter
        const int hh = ui >> 5;
        float p0 = 0.f, p1 = 0.f;
        #pragma unroll 4
        for (int i = 0; i < 32; ++i){
            const int inst = q * 32 + i;
            u32 u = *(const u32*)(xbf + ((long)gb * 128 + inst) * 128 + ui * 2);
            float e = eA[inst][hh];
            p0 += e * bf2f(u & 0xffffu);
            p1 += e * bf2f(u >> 16);
        }
        partials[(size_t)gb * 512 + ui * 8 + 0 + q] = p0;
        partials[(size_t)gb * 512 + ui * 8 + 4 + q] = p1;
    }
}

// ---------------------------------------------------------------------------
// K3a: first-stage reduction over the nb dimension. 128 blocks x 256 threads.
// Block b sums rows b, b+128, ... -> red[b][520] (cols 512,513 = psum).
// ---------------------------------------------------------------------------
__global__ __launch_bounds__(256)
void reduce1(const float* __restrict__ partials, const float* __restrict__ psum,
             float* __restrict__ red, int nb){
    const int b = blockIdx.x, t = threadIdx.x;
    float a0 = 0.f, a1 = 0.f;
    for (int r = b; r < nb; r += 128){
        a0 += partials[(size_t)r * 512 + t];
        a1 += partials[(size_t)r * 512 + t + 256];
    }
    red[b * 520 + t]       = a0;
    red[b * 520 + t + 256] = a1;
    if (t < 2){
        float s = 0.f;
        for (int r = b; r < nb; r += 128) s += psum[r * 2 + t];
        red[b * 520 + 512 + t] = s;
    }
}

// ---------------------------------------------------------------------------
// K3b: combine 128 reduced rows (f64), M, logits, sigmoid, Y_hat. One block,
// all 256 threads active over the 128x520 (266 KB, L2-resident) matrix.
// ---------------------------------------------------------------------------
__global__ __launch_bounds__(256)
void finalize2(const float* __restrict__ red, const float* __restrict__ Wcls,
               const float* __restrict__ bcls, float* __restrict__ out){
    __shared__ double colD[512];
    __shared__ double den[2];
    __shared__ float  M_s[128];
    const int t = threadIdx.x;
    double d0 = 0.0, d1 = 0.0;
    for (int r = 0; r < 128; ++r){
        d0 += (double)red[r * 520 + t];
        d1 += (double)red[r * 520 + t + 256];
    }
    colD[t]       = d0;
    colD[t + 256] = d1;
    if (t < 2){
        double s = 0.0;
        for (int r = 0; r < 128; ++r) s += (double)red[r * 520 + 512 + t];
        den[t] = s;
    }
    __syncthreads();
    if (t < 128){
        // channel c = t; partials column group: ui = c>>1, half = c&1
        const double* p = &colD[(t >> 1) * 8 + (t & 1) * 4];
        M_s[t] = (float)((p[0] + p[1] + p[2] + p[3]) / den[t >> 6]);
    }
    __syncthreads();
    if (t == 0){
        double lg = (double)bcls[0];
        for (int c = 0; c < 128; ++c) lg += (double)M_s[c] * (double)Wcls[c];
        float pr = (float)(1.0 / (1.0 + exp(-lg)));
        out[0] = pr;
        out[1] = (lg >= 0.0) ? 1.f : 0.f;
    }
}

// ---------------------------------------------------------------------------
extern "C" void kernel_launch(void* const* d_in, const int* in_sizes, int n_in,
                              void* d_out, int out_size, void* d_ws, size_t ws_size,
                              hipStream_t stream){
    const float* hG   = (const float*)d_in[0];
    const float* W0   = (const float*)d_in[1];
    const float* b0   = (const float*)d_in[2];
    const float* Wa   = (const float*)d_in[3];
    const float* ba   = (const float*)d_in[4];
    const float* Wb   = (const float*)d_in[5];
    const float* bb   = (const float*)d_in[6];
    const float* Wc   = (const float*)d_in[7];
    const float* bc   = (const float*)d_in[8];
    const float* Wcls = (const float*)d_in[9];
    const float* bcls = (const float*)d_in[10];

    const int N  = in_sizes[0] / L_IN;
    const int nb = (N + 127) / 128;

    char* ws = (char*)d_ws;
    u16* W0sw = (u16*)ws;                                  // 13*8192*2 = 212992 B
    u16* xbf  = (u16*)(ws + 262144);                       // nb*128*128*2 B
    size_t xbytes = (size_t)nb * 128 * 128 * 2;
    size_t poff   = 262144 + ((xbytes + 4095) & ~(size_t)4095);
    float* partials = (float*)(ws + poff);                 // nb*512 f32
    float* psum     = partials + (size_t)nb * 512;         // nb*2 f32
    size_t roff     = poff + (((size_t)nb * 514 * 4 + 4095) & ~(size_t)4095);
    float* red      = (float*)(ws + roff);                 // 128*520 f32 = 266 KB

    prep_w0  <<<(KPAD * 128) / 256, 256, 0, stream>>>(W0, W0sw);
    fc_gemm  <<<nb, 256, 0, stream>>>(hG, W0sw, b0, xbf, N);
    attn_pool<<<nb, 256, 0, stream>>>(xbf, Wa, ba, Wb, bb, Wc, bc, partials, psum, N);
    reduce1  <<<128, 256, 0, stream>>>(partials, psum, red, nb);
    finalize2<<<1, 256, 0, stream>>>(red, Wcls, bcls, (float*)d_out);
}